// Round 15
// baseline (271.694 us; speedup 1.0000x reference)
//
#include <hip/hip_runtime.h>
#include <hip/hip_bf16.h>

typedef unsigned short u16;
typedef float f32x4 __attribute__((ext_vector_type(4)));
typedef __bf16 bf16x8 __attribute__((ext_vector_type(8)));
typedef unsigned short su8v __attribute__((ext_vector_type(8)));
typedef unsigned short su4v __attribute__((ext_vector_type(4)));

#define BB 8
#define NHD 8
#define DD 128
#define NN 1024
#define DIM 1024
#define H3 3072
#define MM 8192
// scale * log2(e), folded into Q weights so softmax is exp2(raw dot)
#define QSC (0.08838834764831845f * 1.4426950408889634f)

__constant__ int   d_IDX[16] = {0,1,2,3, 1,0,3,2, 2,3,0,1, 3,2,1,0};
__constant__ float d_SGN[16] = {1.f,-1.f,-1.f,-1.f, 1.f,1.f,1.f,-1.f,
                                1.f,-1.f,1.f,1.f,  1.f,1.f,-1.f,1.f};

__device__ __forceinline__ f32x4 mfma16(su8v a, su8v b, f32x4 c) {
  return __builtin_amdgcn_mfma_f32_16x16x32_bf16(
      __builtin_bit_cast(bf16x8, a), __builtin_bit_cast(bf16x8, b), c, 0, 0, 0);
}
__device__ __forceinline__ u16 f2b(float f) {  // RNE
  unsigned int u = __builtin_bit_cast(unsigned int, f);
  u += 0x7fffu + ((u >> 16) & 1u);
  return (u16)(u >> 16);
}
__device__ __forceinline__ float b2f(u16 v) {
  unsigned int u = ((unsigned int)v) << 16;
  return __builtin_bit_cast(float, u);
}
typedef const __attribute__((address_space(1))) unsigned int* gas_t;
typedef __attribute__((address_space(3))) unsigned int* las_t;
__device__ __forceinline__ void gll16(const u16* g, u16* l) {
  __builtin_amdgcn_global_load_lds((gas_t)g, (las_t)l, 16, 0, 0);
}

// ---------------------------------------------------------------------------
// prep_weff: effective weights [out_row][in_col] bf16; Q-rows pre-scaled by QSC
// ---------------------------------------------------------------------------
__global__ __launch_bounds__(256) void prep_weff(
    const float* __restrict__ wqkv, const float* __restrict__ wproj,
    u16* __restrict__ weffQ, u16* __restrict__ weffP) {
  int tid = blockIdx.x * 256 + threadIdx.x;
  int stride = gridDim.x * 256;
  for (int i = tid; i < H3 * DIM; i += stride) {
    int row = i >> 10, col = i & 1023;
    int q = row / 768, o = row - q * 768;
    int p = col >> 8, c = col & 255;
    float v = d_SGN[q * 4 + p] * wqkv[(d_IDX[q * 4 + p] * 768 + o) * 256 + c];
    if (o < 256) v *= QSC;  // Q rows
    weffQ[i] = f2b(v);
  }
  for (int i = tid; i < DIM * DIM; i += stride) {
    int row = i >> 10, col = i & 1023;
    int q = row >> 8, o = row & 255;
    int p = col >> 8, c = col & 255;
    weffP[i] = f2b(d_SGN[q * 4 + p] * wproj[(d_IDX[q * 4 + p] * 256 + o) * 256 + c]);
  }
}

// ---------------------------------------------------------------------------
// prep_x: x (B,Cc,4,N) fp32 -> Ax bf16 [8192 (b,n)][1024 (p,c)].
// LDS transpose, layout T[n][pc] stride 264 u16 (16B-aligned su8v reads).
// ---------------------------------------------------------------------------
__global__ __launch_bounds__(256) void prep_x(
    const float* __restrict__ x, u16* __restrict__ Ax) {
  __shared__ u16 T[64 * 264];  // [n][pc], stride 264
  int blk = blockIdx.x;
  int nc = blk & 15;
  int cc = (blk >> 4) & 3;
  int b = blk >> 6;
  int n0 = nc * 64, c0 = cc * 64;
  int tid = threadIdx.x;
  int nseg = tid & 15, rq = tid >> 4;  // rq 0..15
#pragma unroll
  for (int pass = 0; pass < 16; ++pass) {
    int rr = pass * 16 + rq;  // pc local 0..255: p = rr>>6, c = rr&63
    int p = rr >> 6, c = rr & 63;
    float4 f = *(const float4*)(x + (((size_t)(b * 256 + c0 + c)) * 4 + p) * 1024 +
                                n0 + nseg * 4);
    T[(nseg * 4 + 0) * 264 + rr] = f2b(f.x);
    T[(nseg * 4 + 1) * 264 + rr] = f2b(f.y);
    T[(nseg * 4 + 2) * 264 + rr] = f2b(f.z);
    T[(nseg * 4 + 3) * 264 + rr] = f2b(f.w);
  }
  __syncthreads();
  int nl = tid >> 5, lc = tid & 31;
#pragma unroll
  for (int pass = 0; pass < 8; ++pass) {
    int n = pass * 8 + nl;
    su8v v = *(const su8v*)(&T[n * 264 + lc * 8]);
    int pcl = lc * 8;
    *(su8v*)(Ax + (size_t)(b * 1024 + n0 + n) * 1024 + (pcl >> 6) * 256 + c0 +
             (pcl & 63)) = v;
  }
}

// ---------------------------------------------------------------------------
// BK-64 8-wave GEMM core (round-12 measured best for qkv: 60.7us, 850 TF).
// Tile BM x BN (BM+BN == 384), 512 threads = 8 waves of 64x64, 3-slot ring
// (144 KB), ONE barrier per K-tile + counted vmcnt(6); loads for 2 future
// tiles in flight across barriers. LDS rows 64 u16 = 8 x 16B blocks,
// XOR-swizzled (blk ^= row&7); source pre-swizzled identically.
// ---------------------------------------------------------------------------
template <int BM, int BN>
__device__ __forceinline__ void gemm_core64(
    const u16* __restrict__ Ag, const u16* __restrict__ Bg,
    u16* As, u16* Bs, int tid, f32x4 (&acc)[4][4]) {
  constexpr int WN = BN / 64;
  constexpr int AC = BM / 64;
  constexpr int BC = BN / 64;
  constexpr int NT = 16;  // K = 1024 / BK(64)
  int w = tid >> 6, lane = tid & 63, l16 = lane & 15, quad = lane >> 4;
  int wm = w / WN, wn = w % WN;
  int x7 = l16 & 7;
  int srow = lane >> 3;
  int sblk = (lane & 7) ^ srow;

  auto STAGE_A = [&](int tt, int bs) {
#pragma unroll
    for (int c = 0; c < AC; ++c) {
      int r0 = c * 64 + w * 8;
      gll16(Ag + (size_t)(r0 + srow) * 1024 + tt * 64 + sblk * 8,
            As + (size_t)bs * (BM * 64) + r0 * 64);
    }
  };
  auto STAGE_B = [&](int tt, int bs) {
#pragma unroll
    for (int c = 0; c < BC; ++c) {
      int r0 = c * 64 + w * 8;
      gll16(Bg + (size_t)(r0 + srow) * 1024 + tt * 64 + sblk * 8,
            Bs + (size_t)bs * (BN * 64) + r0 * 64);
    }
  };

  STAGE_A(0, 0); STAGE_B(0, 0);
  STAGE_A(1, 1); STAGE_B(1, 1);
  asm volatile("s_waitcnt vmcnt(6)" ::: "memory");
  __builtin_amdgcn_s_barrier();

  int cur = 0, nxt = 1, stg = 2;
  for (int t = 0; t < NT; ++t) {
    const u16* At = As + (size_t)cur * (BM * 64);
    const u16* Bt = Bs + (size_t)cur * (BN * 64);
#pragma unroll
    for (int kk = 0; kk < 2; ++kk) {
      su8v af[4], bf[4];
#pragma unroll
      for (int i = 0; i < 4; ++i)
        af[i] = *(const su8v*)(At + (wm * 64 + i * 16 + l16) * 64 +
                               ((kk * 4 + quad) ^ x7) * 8);
#pragma unroll
      for (int j = 0; j < 4; ++j)
        bf[j] = *(const su8v*)(Bt + (wn * 64 + j * 16 + l16) * 64 +
                               ((kk * 4 + quad) ^ x7) * 8);
      if (t + 2 < NT) {
        if (kk == 0) STAGE_A(t + 2, stg);
        else         STAGE_B(t + 2, stg);
      }
      __builtin_amdgcn_s_setprio(1);
#pragma unroll
      for (int i = 0; i < 4; ++i)
#pragma unroll
        for (int j = 0; j < 4; ++j)
          acc[i][j] = mfma16(af[i], bf[j], acc[i][j]);
      __builtin_amdgcn_s_setprio(0);
    }
    if (t < NT - 2)       asm volatile("s_waitcnt vmcnt(6)" ::: "memory");
    else if (t == NT - 2) asm volatile("s_waitcnt vmcnt(0)" ::: "memory");
    asm volatile("" ::: "memory");
    __builtin_amdgcn_s_barrier();
    asm volatile("" ::: "memory");
    int tmp = cur; cur = nxt; nxt = stg; stg = tmp;
  }
}

// ---------------------------------------------------------------------------
// BK-32 8-wave GEMM core (round-13; measured best for proj via 72 KB ring ->
// 2 blocks/CU). Same schedule, vmcnt(3), rows 32 u16 = 4 x 16B blocks,
// swizzle key (row>>1)&3. All LDS accesses <=2-way (measured 0 conflicts).
// ---------------------------------------------------------------------------
template <int BM, int BN>
__device__ __forceinline__ void gemm_core32(
    const u16* __restrict__ Ag, const u16* __restrict__ Bg,
    u16* As, u16* Bs, int tid, f32x4 (&acc)[4][4]) {
  constexpr int WN = BN / 64;
  constexpr int AC = BM / 128;
  constexpr int BC = BN / 128;
  constexpr int NT = 32;  // K = 1024 / BK(32)
  static_assert(AC + BC == 3, "vmcnt(3) assumes 3 gll per wave per tile");
  int w = tid >> 6, lane = tid & 63, l16 = lane & 15, quad = lane >> 4;
  int wm = w / WN, wn = w % WN;
  int sx = (l16 >> 1) & 3;
  int srow = lane >> 2;
  int sblk = (lane & 3) ^ ((srow >> 1) & 3);

  auto STAGE_A = [&](int tt, int bs) {
#pragma unroll
    for (int c = 0; c < AC; ++c) {
      int r0 = (c * 8 + w) * 16;
      gll16(Ag + (size_t)(r0 + srow) * 1024 + tt * 32 + sblk * 8,
            As + (size_t)bs * (BM * 32) + r0 * 32);
    }
  };
  auto STAGE_B = [&](int tt, int bs) {
#pragma unroll
    for (int c = 0; c < BC; ++c) {
      int r0 = (c * 8 + w) * 16;
      gll16(Bg + (size_t)(r0 + srow) * 1024 + tt * 32 + sblk * 8,
            Bs + (size_t)bs * (BN * 32) + r0 * 32);
    }
  };

  STAGE_A(0, 0); STAGE_B(0, 0);
  STAGE_A(1, 1); STAGE_B(1, 1);
  asm volatile("s_waitcnt vmcnt(3)" ::: "memory");
  __builtin_amdgcn_s_barrier();

  int cur = 0, nxt = 1, stg = 2;
  for (int t = 0; t < NT; ++t) {
    const u16* At = As + (size_t)cur * (BM * 32);
    const u16* Bt = Bs + (size_t)cur * (BN * 32);
    su8v af[4], bf[4];
#pragma unroll
    for (int i = 0; i < 4; ++i)
      af[i] = *(const su8v*)(At + (wm * 64 + i * 16 + l16) * 32 +
                             ((quad ^ sx) * 8));
#pragma unroll
    for (int j = 0; j < 4; ++j)
      bf[j] = *(const su8v*)(Bt + (wn * 64 + j * 16 + l16) * 32 +
                             ((quad ^ sx) * 8));
    if (t + 2 < NT) {
      STAGE_A(t + 2, stg);
      STAGE_B(t + 2, stg);
    }
    __builtin_amdgcn_s_setprio(1);
#pragma unroll
    for (int i = 0; i < 4; ++i)
#pragma unroll
      for (int j = 0; j < 4; ++j)
        acc[i][j] = mfma16(af[i], bf[j], acc[i][j]);
    __builtin_amdgcn_s_setprio(0);
    if (t < NT - 2)       asm volatile("s_waitcnt vmcnt(3)" ::: "memory");
    else if (t == NT - 2) asm volatile("s_waitcnt vmcnt(0)" ::: "memory");
    if (t < NT - 1) {
      asm volatile("" ::: "memory");
      __builtin_amdgcn_s_barrier();
      asm volatile("" ::: "memory");
    }
    int tmp = cur; cur = nxt; nxt = stg; stg = tmp;
  }
}

// ---------------------------------------------------------------------------
// QKV GEMM (round-12 config, measured 60.7us): tile = 256 (bn) x 128 (chan),
// BK-64 core. Grid 32x24 = 768 blocks = 3.0 rounds (no tail loss).
// V store: 4-key halves of each 8-key group swapped when (dl&2) (npos^4) so
// attn's bijective Vt granule swizzle sees key-linear 16B blocks.
// ---------------------------------------------------------------------------
__global__ __launch_bounds__(512, 2) void gemm_qkv_mfma(
    const u16* __restrict__ Ax, const u16* __restrict__ weffQ,
    const float* __restrict__ bqkv,
    u16* __restrict__ Qb, u16* __restrict__ Kb, u16* __restrict__ VbT) {
  __shared__ u16 smem[3 * 384 * 64];  // 144 KB: 3-slot ring, A tile + B tile
  int bn0 = blockIdx.x * 256;
  int col0 = blockIdx.y * 128;
  int q = col0 / 768;
  int off = col0 - q * 768;
  int sel = off >> 8;  // 0=Q 1=K 2=V (uniform)
  int head = (q * 256 + (off & 255)) >> 7;
  int tid = threadIdx.x;
  int w = tid >> 6, lane = tid & 63, l16 = lane & 15, quad = lane >> 4;
  f32x4 acc[4][4];
#pragma unroll
  for (int i = 0; i < 4; ++i)
#pragma unroll
    for (int j = 0; j < 4; ++j) acc[i][j] = (f32x4){0.f, 0.f, 0.f, 0.f};

  if (sel == 2) {
    // ---- V: m=bn (256), n=chan (128) ----
    gemm_core64<256, 128>(Ax + (size_t)bn0 * 1024, weffQ + (size_t)col0 * 1024,
                          smem, smem + 3 * 256 * 64, tid, acc);
    int wm = w >> 1, wn = w & 1;
#pragma unroll
    for (int j = 0; j < 4; ++j) {
      int dl = wn * 64 + j * 16 + l16;
      float bias = bqkv[col0 + dl];
      int hswap = (dl & 2) << 1;  // swap 4-key halves when d bit1 set
#pragma unroll
      for (int i = 0; i < 4; ++i) {
        int m = bn0 + wm * 64 + i * 16 + quad * 4;
        int b = m >> 10, npos = m & 1023;
        int bh = b * NHD + head;
        su4v pk;
#pragma unroll
        for (int r = 0; r < 4; ++r) pk[r] = f2b(acc[i][j][r] + bias);
        *(su4v*)(VbT + ((size_t)bh * DD + dl) * NN + (npos ^ hswap)) = pk;
      }
    }
  } else {
    // ---- Q/K: m=chan (128), n=bn (256) ----
    gemm_core64<128, 256>(weffQ + (size_t)col0 * 1024, Ax + (size_t)bn0 * 1024,
                          smem, smem + 3 * 128 * 64, tid, acc);
    int wm = w >> 2, wn = w & 3;
    u16* dst = (sel == 0) ? Qb : Kb;
    float sc = (sel == 0) ? (float)QSC : 1.0f;
#pragma unroll
    for (int i = 0; i < 4; ++i) {
      int dbase = wm * 64 + i * 16 + quad * 4;
      float4 b4 = *(const float4*)(bqkv + col0 + dbase);
#pragma unroll
      for (int j = 0; j < 4; ++j) {
        int n = bn0 + wn * 64 + j * 16 + l16;
        int b = n >> 10, npos = n & 1023;
        int bh = b * NHD + head;
        su4v pk;
        pk[0] = f2b(acc[i][j][0] + b4.x * sc);
        pk[1] = f2b(acc[i][j][1] + b4.y * sc);
        pk[2] = f2b(acc[i][j][2] + b4.z * sc);
        pk[3] = f2b(acc[i][j][3] + b4.w * sc);
        *(su4v*)(dst + ((size_t)bh * NN + npos) * DD + dbase) = pk;
      }
    }
  }
}

// ---------------------------------------------------------------------------
// Flash attention, FULL-K: 512 blocks = qt(8) x bh(64). 128 q x 1024 keys,
// KVBLK=32 -> 32 K-tiles. Round-15: 2-slot ring (32 KB total LDS) -> 4
// blocks/CU = 16 waves/CU (was 48 KB -> 2 blocks, 19% occupancy; attn's
// floors MFMA ~4us / VALU ~10us / DS ~20us vs ~53us wall = pipes not
// overlapped for lack of TLP). Pipelining kept: STAGE(kt+1) issues at TOP
// of kt (latency hides under the whole compute body), vmcnt(0)+barrier at
// BOTTOM. WAR safe: stage writes slot s^1 while waves read s; barrier
// separates readers of s from its overwrite at kt+2.
// In-register P; PV + rowsum at K=32 (two 16-key P slices concatenated;
// V B-fragment = concat of the same two b64 granule reads). accL = full
// row-sums -> normalize in-register, write final AO directly.
// Bank layout (conflict-free, measured 0): Ks slot = blk ^ (key&15);
// Vt granule slot = nat ^ (l16>>1), V stored globally with 4-key halves
// swapped when d&2, staged with block key (dv>>2)&3.
// No launch_bounds min-waves (rounds 6/7: caps below natural regs => spill).
// ---------------------------------------------------------------------------
__global__ __launch_bounds__(256) void attn_mfma(
    const u16* __restrict__ Qb, const u16* __restrict__ Kb,
    const u16* __restrict__ VbT, u16* __restrict__ AO) {
  __shared__ u16 Ks[2 * 32 * 128];  // 16 KB, 4-bit xor-swizzled blocks
  __shared__ u16 Vt[2 * 128 * 32];  // 16 KB, bijective granule swizzle
  int blk = blockIdx.x;
  int bh = blk & 63;
  int qt = blk >> 6;
  int n0 = qt * 128;
  int tid = threadIdx.x;
  int w = tid >> 6, lane = tid & 63, l16 = lane & 15, quad = lane >> 4;
  const u16* Qg = Qb + ((size_t)bh * NN + n0) * DD;
  const u16* Kg = Kb + (size_t)bh * NN * DD;
  const u16* Vg = VbT + (size_t)bh * DD * NN;
  int s7 = l16 >> 1;  // Vt granule swizzle key

  auto STAGE = [&](int kt, int s) {
    int c0 = kt * 32;
#pragma unroll
    for (int t = 0; t < 2; ++t) {
      int ci = w * 2 + t;  // 0..7
      // K: 1KB = 4 rows x 256B; block slot holds global blk^(key&15)
      int krow = ci * 4 + (lane >> 4);
      int kblk = (lane & 15) ^ (krow & 15);
      gll16(Kg + (size_t)(c0 + krow) * DD + kblk * 8, Ks + s * 4096 + ci * 512);
      // V: 1KB = 16 rows x 64B; 16B block slot = nat ^ ((dv>>2)&3); the
      // within-block half order comes pre-swapped from global when dv&2
      int dv = ci * 16 + (lane >> 2);
      int vblk = (lane & 3) ^ ((dv >> 2) & 3);
      gll16(Vg + (size_t)dv * NN + c0 + vblk * 8, Vt + s * 4096 + ci * 512);
    }
  };

  su8v qreg[2][4];  // B-fragment: n=q (l16), k=d
#pragma unroll
  for (int mi = 0; mi < 2; ++mi)
#pragma unroll
    for (int ch = 0; ch < 4; ++ch)
      qreg[mi][ch] = *(const su8v*)(Qg + (size_t)(w * 32 + mi * 16 + l16) * DD +
                                    ch * 32 + quad * 8);

  su8v ones8;
#pragma unroll
  for (int e = 0; e < 8; ++e) ones8[e] = 0x3F80;
  f32x4 accL[2];
  accL[0] = (f32x4){0.f, 0.f, 0.f, 0.f};
  accL[1] = (f32x4){0.f, 0.f, 0.f, 0.f};
  f32x4 accO[2][8];
#pragma unroll
  for (int mi = 0; mi < 2; ++mi)
#pragma unroll
    for (int dt = 0; dt < 8; ++dt) accO[mi][dt] = (f32x4){0.f, 0.f, 0.f, 0.f};

  STAGE(0, 0);
  asm volatile("s_waitcnt vmcnt(0)" ::: "memory");
  __builtin_amdgcn_s_barrier();

  for (int kt = 0; kt < 32; ++kt) {
    int s = kt & 1;
    const u16* Kc = Ks + s * 4096;
    const u16* Vc = Vt + s * 4096;
    if (kt + 1 < 32) STAGE(kt + 1, s ^ 1);

    // QK^T for both 16-key slices -> packed P (kept per slice)
    su4v pk[2][2];  // [mi][j]
#pragma unroll
    for (int j = 0; j < 2; ++j) {
      f32x4 s0 = (f32x4){0.f, 0.f, 0.f, 0.f};
      f32x4 s1 = (f32x4){0.f, 0.f, 0.f, 0.f};
#pragma unroll
      for (int ch = 0; ch < 4; ++ch) {
        su8v kf = *(const su8v*)(Kc + (j * 16 + l16) * 128 +
                                 (((ch * 4 + quad) ^ l16) * 8));
        s0 = mfma16(kf, qreg[0][ch], s0);
        s1 = mfma16(kf, qreg[1][ch], s1);
      }
      su4v p0, p1;
#pragma unroll
      for (int r = 0; r < 4; ++r) {
        float pa = __builtin_exp2f(s0[r]);
        p0[r] = (u16)(__builtin_bit_cast(unsigned int, pa) >> 16);
        float pb = __builtin_exp2f(s1[r]);
        p1[r] = (u16)(__builtin_bit_cast(unsigned int, pb) >> 16);
      }
      pk[0][j] = p0;
      pk[1][j] = p1;
    }
    // concat the two slices -> K=32 A-fragments
    su8v p80, p81;
#pragma unroll
    for (int e = 0; e < 4; ++e) {
      p80[e] = pk[0][0][e]; p80[4 + e] = pk[0][1][e];
      p81[e] = pk[1][0][e]; p81[4 + e] = pk[1][1][e];
    }
    accL[0] = mfma16(p80, ones8, accL[0]);
    accL[1] = mfma16(p81, ones8, accL[1]);
    // PV at K=32: B-fragment = concat of the j0/j1 granule reads
#pragma unroll
    for (int dt = 0; dt < 8; ++dt) {
      const u16* vrow = Vc + (dt * 16 + l16) * 32;
      su4v va = *(const su4v*)(vrow + ((quad ^ s7) * 4));
      su4v vb = *(const su4v*)(vrow + (((4 + quad) ^ s7) * 4));
      su8v v8;
#pragma unroll
      for (int e = 0; e < 4; ++e) { v8[e] = va[e]; v8[4 + e] = vb[e]; }
      accO[0][dt] = mfma16(p80, v8, accO[0][dt]);
      accO[1][dt] = mfma16(p81, v8, accO[1][dt]);
    }

    if (kt + 1 < 32) {
      asm volatile("s_waitcnt vmcnt(0)" ::: "memory");
      asm volatile("" ::: "memory");
      __builtin_amdgcn_s_barrier();
      asm volatile("" ::: "memory");
    }
  }

  // normalize in-register and write final AO[b*1024+n][head*128+d]
  int bb = bh >> 3, head = bh & 7;
#pragma unroll
  for (int mi = 0; mi < 2; ++mi) {
#pragma unroll
    for (int r = 0; r < 4; ++r) {
      int row = w * 32 + mi * 16 + quad * 4 + r;
      float iv = 1.0f / accL[mi][r];
      size_t base = ((size_t)(bb * 1024) + n0 + row) * 1024 + head * 128;
#pragma unroll
      for (int dt = 0; dt < 8; ++dt)
        AO[base + dt * 16 + l16] = f2b(accO[mi][dt][r] * iv);
    }
  }
}

// ---------------------------------------------------------------------------
// quaternion depthwise 3x3 conv (fp32) — writes PE term into workspace
// ---------------------------------------------------------------------------
__global__ __launch_bounds__(256) void qdwconv_kernel(
    const float* __restrict__ x, const float* __restrict__ wpe,
    const float* __restrict__ bpe, float* __restrict__ pe) {
  int blk = blockIdx.x;
  int co = blk & 255;
  int b = blk >> 8;
  __shared__ float pl[4][34 * 34];
  __shared__ float wsm[4][9];
  int tid = threadIdx.x;
  for (int i = tid; i < 4 * 34 * 34; i += 256) ((float*)pl)[i] = 0.f;
  if (tid < 36) wsm[tid / 9][tid % 9] = wpe[((tid / 9) * 256 + co) * 9 + tid % 9];
  __syncthreads();
  for (int i = tid; i < 4 * 1024; i += 256) {
    int p = i >> 10, n = i & 1023;
    int h = n >> 5, ww = n & 31;
    pl[p][(h + 1) * 34 + (ww + 1)] =
        x[(((size_t)b * 256 + co) * 4 + p) * 1024 + n];
  }
  __syncthreads();
  for (int n = tid; n < 1024; n += 256) {
    int h = n >> 5, ww = n & 31;
    float in[4][9];
#pragma unroll
    for (int p = 0; p < 4; ++p)
#pragma unroll
      for (int t = 0; t < 9; ++t)
        in[p][t] = pl[p][(h + t / 3) * 34 + (ww + t % 3)];
#pragma unroll
    for (int q = 0; q < 4; ++q) {
      float acc = bpe[q * 256 + co];
#pragma unroll
      for (int p = 0; p < 4; ++p) {
        int idx = d_IDX[q * 4 + p];
        float s = d_SGN[q * 4 + p];
        float sub = 0.f;
#pragma unroll
        for (int t = 0; t < 9; ++t) sub += in[p][t] * wsm[idx][t];
        acc += s * sub;
      }
      pe[(((size_t)b * 256 + co) * 4 + q) * 1024 + n] = acc;
    }
  }
}

// ---------------------------------------------------------------------------
// proj GEMM (round-13 config): tile = 256 (bn) x 128 (q,o), BK-32 core,
// 72 KB ring -> 2 blocks/CU. Grid 32x8 = 256 blocks = 1.0 round.
// ---------------------------------------------------------------------------
__global__ __launch_bounds__(512) void gemm_proj_mfma(
    const u16* __restrict__ AO, const u16* __restrict__ weffP,
    const float* __restrict__ bproj, const float* __restrict__ pe,
    float* __restrict__ out) {
  __shared__ u16 smem[3 * 384 * 32];  // 72 KB ring
  int n0 = blockIdx.x * 256;
  int m0 = blockIdx.y * 128;
  int tid = threadIdx.x;
  f32x4 acc[4][4];
#pragma unroll
  for (int i = 0; i < 4; ++i)
#pragma unroll
    for (int j = 0; j < 4; ++j) acc[i][j] = (f32x4){0.f, 0.f, 0.f, 0.f};
  gemm_core32<128, 256>(weffP + (size_t)m0 * 1024, AO + (size_t)n0 * 1024,
                        smem, smem + 3 * 128 * 32, tid, acc);

  int w = tid >> 6, lane = tid & 63, l16 = lane & 15, quad = lane >> 4;
  int wm = w >> 2, wn = w & 3;
#pragma unroll
  for (int i = 0; i < 4; ++i) {
#pragma unroll
    for (int r = 0; r < 4; ++r) {
      int mrow = m0 + wm * 64 + i * 16 + quad * 4 + r;
      int q = mrow >> 8, o = mrow & 255;
      float bias = bproj[mrow];
#pragma unroll
      for (int j = 0; j < 4; ++j) {
        int n = n0 + wn * 64 + j * 16 + l16;
        int b = n >> 10, npos = n & 1023;
        size_t oidx = (((size_t)b * 256 + o) * 4 + q) * 1024 + npos;
        out[oidx] = pe[oidx] + acc[i][j][r] + bias;
      }
    }
  }
}

// ---------------------------------------------------------------------------
extern "C" void kernel_launch(void* const* d_in, const int* in_sizes, int n_in,
                              void* d_out, int out_size, void* d_ws,
                              size_t ws_size, hipStream_t stream) {
  const float* x      = (const float*)d_in[0];
  const float* w_qkv  = (const float*)d_in[1];
  const float* b_qkv  = (const float*)d_in[2];
  const float* w_proj = (const float*)d_in[3];
  const float* b_proj = (const float*)d_in[4];
  const float* w_pe   = (const float*)d_in[5];
  const float* b_pe   = (const float*)d_in[6];
  float* out = (float*)d_out;

  u16* ws = (u16*)d_ws;
  u16* weffQ = ws;                                   // 3072*1024
  u16* weffP = weffQ + (size_t)H3 * DIM;             // 1024*1024
  u16* Ax    = weffP + (size_t)DIM * DIM;            // 8192*1024
  u16* Qb    = Ax + (size_t)MM * DIM;                // 64*1024*128
  u16* Kb    = Qb + (size_t)BB * NHD * NN * DD;      // 64*1024*128
  u16* VbT   = Kb + (size_t)BB * NHD * NN * DD;      // 64*128*1024
  u16* AO    = VbT + (size_t)BB * NHD * DD * NN;     // 8192*1024
  float* PE  = (float*)(AO + (size_t)MM * DIM);      // 8192*1024 fp32

  hipLaunchKernelGGL(prep_weff, dim3(4096), dim3(256), 0, stream,
                     w_qkv, w_proj, weffQ, weffP);
  hipLaunchKernelGGL(prep_x, dim3(512), dim3(256), 0, stream, x, Ax);
  hipLaunchKernelGGL(gemm_qkv_mfma, dim3(MM / 256, H3 / 128), dim3(512), 0,
                     stream, Ax, weffQ, b_qkv, Qb, Kb, VbT);
  hipLaunchKernelGGL(attn_mfma, dim3(512), dim3(256), 0, stream,
                     Qb, Kb, VbT, AO);
  hipLaunchKernelGGL(qdwconv_kernel, dim3(BB * 256), dim3(256), 0, stream,
                     x, w_pe, b_pe, PE);
  hipLaunchKernelGGL(gemm_proj_mfma, dim3(MM / 256, DIM / 128), dim3(512), 0,
                     stream, AO, weffP, b_proj, PE, out);
}